// Round 1
// baseline (388.004 us; speedup 1.0000x reference)
//
#include <hip/hip_runtime.h>
#include <cmath>

// Problem constants
#define M_B   8
#define LQ    256
#define N_B   64
#define LR    512
#define COND  64
#define PRED  32
#define DH    128
#define QN    193      // LQ-COND+1
#define KN    417      // (LR-PRED)-COND+1
#define QROW_PAD 200   // per-m padded q rows
#define MQ_TOT   1600  // 8*200
#define KPAD     448   // padded kpos
#define LDSW     132   // padded LDS row (floats), 528B = 33*16B aligned

// ---------------- K0: cumsums, minmax offsets/scales, mc (mean conv) ----------------
__global__ void k0_scan(const float* __restrict__ q, const float* __restrict__ r,
                        float* cs_q, float* cs_r, float* mc,
                        float* q_off, float* q_scale, float* k_off, float* k_scale,
                        const float* __restrict__ mw, const float* __restrict__ mb) {
    __shared__ float x[512];
    __shared__ float s[512];
    __shared__ float P[256];
    int b = blockIdx.x, t = threadIdx.x;
    if (b < M_B) {
        // ---- query row b (len 256) ----
        x[t] = q[b * 256 + t];
        __syncthreads();
        s[t] = x[t];
        __syncthreads();
        for (int off = 1; off < 256; off <<= 1) {
            float v = (t >= off) ? s[t - off] : 0.f;
            __syncthreads();
            s[t] += v;
            __syncthreads();
        }
        cs_q[b * 256 + t] = s[t];
        // mc[t] = sum_j mw[j]*query[t+j-63] (zero pad) + m_bias
        float acc = mb[0];
        for (int j = 0; j < 64; j++) {
            int qi = t + j - 63;
            if (qi >= 0) acc += mw[j] * x[qi];
        }
        mc[b * 256 + t] = acc;
        // q offset/scale per qpos
        if (t < QROW_PAD) {
            if (t < QN) {
                float mn = s[t], mx = s[t];
                for (int j = 1; j < 64; j++) {
                    float v = s[t + j];
                    mn = fminf(mn, v); mx = fmaxf(mx, v);
                }
                float sc = mx - mn; if (sc == 0.f) sc = 1.f;
                q_off[b * QROW_PAD + t] = mn;
                q_scale[b * QROW_PAD + t] = sc;
            } else {
                q_off[b * QROW_PAD + t] = 0.f;
                q_scale[b * QROW_PAD + t] = 1.f;
            }
        }
    } else {
        // ---- ref row (len 512): pair-scan ----
        int n = b - M_B;
        x[t] = r[n * 512 + t];
        x[t + 256] = r[n * 512 + t + 256];
        __syncthreads();
        P[t] = x[2 * t] + x[2 * t + 1];
        __syncthreads();
        for (int off = 1; off < 256; off <<= 1) {
            float v = (t >= off) ? P[t - off] : 0.f;
            __syncthreads();
            P[t] += v;
            __syncthreads();
        }
        s[2 * t + 1] = P[t];
        s[2 * t]     = P[t] - x[2 * t + 1];
        __syncthreads();
        cs_r[n * 512 + t] = s[t];
        cs_r[n * 512 + t + 256] = s[t + 256];
        // k offset/scale (windows only touch cs[0..479])
        for (int p = t; p < KPAD; p += 256) {
            if (p < KN) {
                float mn = s[p], mx = s[p];
                for (int j = 1; j < 64; j++) {
                    float v = s[p + j];
                    mn = fminf(mn, v); mx = fmaxf(mx, v);
                }
                float sc = mx - mn; if (sc == 0.f) sc = 1.f;
                k_off[n * KPAD + p] = mn;
                k_scale[n * KPAD + p] = sc;
            } else {
                k_off[n * KPAD + p] = 0.f;
                k_scale[n * KPAD + p] = 1.f;
            }
        }
    }
}

// ---------------- K1: q features (minmax conv on cumsum) ----------------
__global__ void k1_qfeat(const float* __restrict__ cs_q, const float* __restrict__ q_off,
                         const float* __restrict__ q_scale,
                         const float* __restrict__ qw, const float* __restrict__ qb,
                         float* qfeat) {
    __shared__ float w[128 * 65];
    __shared__ float wsum[128];
    __shared__ float csS[80];
    __shared__ float offS[16], sclS[16];
    int m = blockIdx.x, chunk = blockIdx.y, t = threadIdx.x;
    int qbase = chunk * 16;
    for (int i = t; i < 8192; i += 256) {
        int h = i >> 6, j = i & 63;
        w[h * 65 + j] = qw[i];
    }
    if (t < 80) {
        int ci = qbase + t;
        csS[t] = (ci < 256) ? cs_q[m * 256 + ci] : 0.f;
    }
    if (t < 16) {
        int qpos = qbase + t;
        if (qpos < QN) { offS[t] = q_off[m * QROW_PAD + qpos]; sclS[t] = q_scale[m * QROW_PAD + qpos]; }
        else { offS[t] = 0.f; sclS[t] = 1.f; }
    }
    __syncthreads();
    if (t < 128) {
        float sm = 0.f;
        for (int j = 0; j < 64; j++) sm += w[t * 65 + j];
        wsum[t] = sm;
    }
    __syncthreads();
    int h = t & 127, ql0 = t >> 7;
    float bias = qb[h];
    for (int ql = ql0; ql < 16; ql += 2) {
        int qpos = qbase + ql;
        if (qpos >= QROW_PAD) continue;
        float raw = 0.f;
        #pragma unroll 8
        for (int j = 0; j < 64; j++) raw += w[h * 65 + j] * csS[ql + j];
        float val = 0.f;
        if (qpos < QN) val = (raw - offS[ql] * wsum[h]) / sclS[ql] + bias;
        qfeat[(m * QROW_PAD + qpos) * 128 + h] = val;
    }
}

// ---------------- K2: k/v features ----------------
__global__ void k2_kv(const float* __restrict__ cs_r, const float* __restrict__ ref,
                      const float* __restrict__ k_off, const float* __restrict__ k_scale,
                      const float* __restrict__ kw, const float* __restrict__ kb,
                      const float* __restrict__ vw, const float* __restrict__ vb,
                      float* kfeat, float* vfeat) {
    __shared__ float w[128 * 65];
    __shared__ float vwS[128 * 33];
    __shared__ float wsum[128];
    __shared__ float csS[128];
    __shared__ float refS[96];
    __shared__ float koS[64], ksS[64];
    int n = blockIdx.x, chunk = blockIdx.y, t = threadIdx.x;
    int kbase = chunk * 64;
    for (int i = t; i < 8192; i += 256) { int h = i >> 6, j = i & 63; w[h * 65 + j] = kw[i]; }
    for (int i = t; i < 4096; i += 256) { int h = i >> 5, j = i & 31; vwS[h * 33 + j] = vw[i]; }
    if (t < 128) { int ci = kbase + t; csS[t] = (ci < 512) ? cs_r[n * 512 + ci] : 0.f; }
    if (t < 96)  { int ri = 64 + kbase + t; refS[t] = (ri < 512) ? ref[n * 512 + ri] : 0.f; }
    if (t < 64) {
        int kp = kbase + t;
        if (kp < KN) { koS[t] = k_off[n * KPAD + kp]; ksS[t] = k_scale[n * KPAD + kp]; }
        else { koS[t] = 0.f; ksS[t] = 1.f; }
    }
    __syncthreads();
    if (t < 128) {
        float sm = 0.f;
        for (int j = 0; j < 64; j++) sm += w[t * 65 + j];
        wsum[t] = sm;
    }
    __syncthreads();
    int h = t & 127, kl0 = t >> 7;
    float kbia = kb[h], vbia = vb[h];
    for (int kl = kl0; kl < 64; kl += 2) {
        int kp = kbase + kl;
        float kraw = 0.f;
        #pragma unroll 8
        for (int j = 0; j < 64; j++) kraw += w[h * 65 + j] * csS[kl + j];
        float vraw = 0.f;
        #pragma unroll 8
        for (int j = 0; j < 32; j++) vraw += vwS[h * 33 + j] * refS[kl + j];
        float kval = 0.f, vval = 0.f;
        if (kp < KN) {
            float inv = 1.f / ksS[kl];
            kval = (kraw - koS[kl] * wsum[h]) * inv + kbia;
            vval = vraw * inv + vbia;
        }
        kfeat[(n * KPAD + kp) * 128 + h] = kval;
        vfeat[(n * KPAD + kp) * 128 + h] = vval;
    }
}

// ---------------- K3: score matmul + max/argmax over kpos ----------------
// grid (25 mq-tiles, 64 n), 256 threads. One block owns all 417 kpos for its
// (64 q-rows, n) -> direct write, no atomics. numpy tie-break: smallest kpos.
__launch_bounds__(256)
__global__ void k3_score(const float* __restrict__ qfeat, const float* __restrict__ kfeat,
                         float* bscore, int* bidx) {
    __shared__ float Qs[64 * LDSW];
    __shared__ float Ks[64 * LDSW];
    int tile = blockIdx.x, n = blockIdx.y, t = threadIdx.x;
    int tx = t & 15, ty = t >> 4;
    int mqbase = tile * 64;
    for (int f = t; f < 2048; f += 256) {
        int row = f >> 5, c4 = f & 31;
        *(float4*)&Qs[row * LDSW + c4 * 4] = *(const float4*)&qfeat[(mqbase + row) * 128 + c4 * 4];
    }
    float bs[4]; int bi[4];
    #pragma unroll
    for (int r = 0; r < 4; r++) { bs[r] = -INFINITY; bi[r] = 0; }
    const float* kbp = kfeat + n * KPAD * 128;
    for (int kt = 0; kt < 7; kt++) {
        int kbase = kt * 64;
        __syncthreads();
        for (int f = t; f < 2048; f += 256) {
            int row = f >> 5, c4 = f & 31;
            *(float4*)&Ks[row * LDSW + c4 * 4] = *(const float4*)&kbp[(kbase + row) * 128 + c4 * 4];
        }
        __syncthreads();
        float acc[4][4];
        #pragma unroll
        for (int r = 0; r < 4; r++)
            #pragma unroll
            for (int c = 0; c < 4; c++) acc[r][c] = 0.f;
        #pragma unroll 4
        for (int kk = 0; kk < 128; kk += 4) {
            float4 qv[4], kv[4];
            #pragma unroll
            for (int r = 0; r < 4; r++) qv[r] = *(float4*)&Qs[(ty + 16 * r) * LDSW + kk];
            #pragma unroll
            for (int c = 0; c < 4; c++) kv[c] = *(float4*)&Ks[(tx + 16 * c) * LDSW + kk];
            #pragma unroll
            for (int r = 0; r < 4; r++)
                #pragma unroll
                for (int c = 0; c < 4; c++)
                    acc[r][c] += qv[r].x * kv[c].x + qv[r].y * kv[c].y +
                                 qv[r].z * kv[c].z + qv[r].w * kv[c].w;
        }
        #pragma unroll
        for (int c = 0; c < 4; c++) {
            int kp = kbase + tx + 16 * c;
            if (kp < KN) {
                #pragma unroll
                for (int r = 0; r < 4; r++) {
                    float s = acc[r][c];
                    if (s > bs[r] || (s == bs[r] && kp < bi[r])) { bs[r] = s; bi[r] = kp; }
                }
            }
        }
    }
    // reduce across the 16 tx lanes sharing each q-row
    #pragma unroll
    for (int r = 0; r < 4; r++) {
        float s = bs[r]; int i0 = bi[r];
        for (int msk = 1; msk < 16; msk <<= 1) {
            float os = __shfl_xor(s, msk, 64);
            int   oi = __shfl_xor(i0, msk, 64);
            if (os > s || (os == s && oi < i0)) { s = os; i0 = oi; }
        }
        if (tx == 0) {
            int mq = mqbase + ty + 16 * r;
            if ((mq % QROW_PAD) < QN) {
                bscore[mq * 64 + n] = s;
                bidx[mq * 64 + n] = i0;
            }
        }
    }
}

// ---------------- K4: softmax + gather-weight V + projection epilogue ----------------
__global__ void k4_out(const float* __restrict__ qfeat, const float* __restrict__ vfeat,
                       const float* __restrict__ bscore, const int* __restrict__ bidx,
                       const float* __restrict__ q_scale, const float* __restrict__ mc,
                       const float* __restrict__ mkey,
                       const float* __restrict__ ow, const float* __restrict__ ob,
                       float* out) {
    __shared__ float sL[64]; __shared__ int iL[64];
    __shared__ float rsL[64];
    __shared__ float redA[128];
    __shared__ float wL[128];
    int bid = blockIdx.x, t = threadIdx.x;
    int m = bid / QN, qpos = bid - m * QN;
    int mq = m * QROW_PAD + qpos;
    if (t < 64) { sL[t] = bscore[mq * 64 + t]; iL[t] = bidx[mq * 64 + t]; }
    // m_score = dot(qfeat_row, m_key)
    redA[t] = qfeat[mq * 128 + t] * mkey[t];
    __syncthreads();
    for (int off = 64; off > 0; off >>= 1) {
        if (t < off) redA[t] += redA[t + off];
        __syncthreads();
    }
    float msv = redA[0];
    __syncthreads();
    // max over the 64 ref scores (then include msv)
    redA[t] = (t < 64) ? sL[t] : -INFINITY;
    __syncthreads();
    for (int off = 64; off > 0; off >>= 1) {
        if (t < off) redA[t] = fmaxf(redA[t], redA[t + off]);
        __syncthreads();
    }
    float mx = fmaxf(redA[0], msv);
    __syncthreads();
    float e = (t < 64) ? expf(sL[t] - mx) : 0.f;
    redA[t] = e;
    if (t < 64) rsL[t] = e;
    __syncthreads();
    for (int off = 64; off > 0; off >>= 1) {
        if (t < off) redA[t] += redA[t + off];
        __syncthreads();
    }
    float ems = expf(msv - mx);
    float inv = 1.f / (redA[0] + ems);
    float msw = ems * inv;
    __syncthreads();
    if (t < 64) rsL[t] *= inv;
    __syncthreads();
    // w[h] = sum_n rs_n * v[n, idx_n, h]
    float acc = 0.f;
    for (int nn = 0; nn < 64; nn++) {
        acc += rsL[nn] * vfeat[(nn * KPAD + iL[nn]) * 128 + t];
    }
    wL[t] = acc;
    __syncthreads();
    if (t < 32) {
        float p = 0.f;
        #pragma unroll 8
        for (int h = 0; h < 128; h++) p += wL[h] * ow[t * 128 + h];
        p += (1.f - msw) * ob[t];
        float outv = q_scale[mq] * p + msw * mc[m * 256 + 32 + qpos + t];
        out[(m * QN + qpos) * 32 + t] = outv;
    }
}

extern "C" void kernel_launch(void* const* d_in, const int* in_sizes, int n_in,
                              void* d_out, int out_size, void* d_ws, size_t ws_size,
                              hipStream_t stream) {
    const float* query = (const float*)d_in[0];
    const float* ref   = (const float*)d_in[1];
    const float* qw    = (const float*)d_in[2];
    const float* qb    = (const float*)d_in[3];
    const float* kw    = (const float*)d_in[4];
    const float* kb    = (const float*)d_in[5];
    const float* vw    = (const float*)d_in[6];
    const float* vb    = (const float*)d_in[7];
    const float* mw    = (const float*)d_in[8];
    const float* mb    = (const float*)d_in[9];
    const float* ow    = (const float*)d_in[10];
    const float* ob    = (const float*)d_in[11];
    const float* mkey  = (const float*)d_in[12];
    float* out = (float*)d_out;

    float* ws = (float*)d_ws;
    float* cs_q    = ws;                    // 8*256      = 2048
    float* cs_r    = cs_q + 2048;           // 64*512     = 32768
    float* mc      = cs_r + 32768;          // 8*256      = 2048
    float* q_off   = mc + 2048;             // 8*200      = 1600
    float* q_scale = q_off + 1600;          // 1600
    float* k_off   = q_scale + 1600;        // 64*448     = 28672
    float* k_scale = k_off + 28672;         // 28672
    float* qfeat   = k_scale + 28672;       // 1600*128   = 204800
    float* kfeat   = qfeat + 204800;        // 64*448*128 = 3670016
    float* vfeat   = kfeat + 3670016;       // 3670016
    float* bscore  = vfeat + 3670016;       // 1600*64    = 102400
    int*   bidx    = (int*)(bscore + 102400); // 102400

    hipLaunchKernelGGL(k0_scan, dim3(72), dim3(256), 0, stream,
                       query, ref, cs_q, cs_r, mc, q_off, q_scale, k_off, k_scale, mw, mb);
    hipLaunchKernelGGL(k1_qfeat, dim3(8, 13), dim3(256), 0, stream,
                       cs_q, q_off, q_scale, qw, qb, qfeat);
    hipLaunchKernelGGL(k2_kv, dim3(64, 7), dim3(256), 0, stream,
                       cs_r, ref, k_off, k_scale, kw, kb, vw, vb, kfeat, vfeat);
    hipLaunchKernelGGL(k3_score, dim3(25, 64), dim3(256), 0, stream,
                       qfeat, kfeat, bscore, bidx);
    hipLaunchKernelGGL(k4_out, dim3(QN * M_B), dim3(128), 0, stream,
                       qfeat, vfeat, bscore, bidx, q_scale, mc, mkey, ow, ob, out);
}

// Round 2
// 225.214 us; speedup vs baseline: 1.7228x; 1.7228x over previous
//
#include <hip/hip_runtime.h>
#include <cmath>

// Problem constants
#define M_B   8
#define LQ    256
#define N_B   64
#define LR    512
#define COND  64
#define PRED  32
#define DH    128
#define QN    193      // LQ-COND+1
#define KN    417      // (LR-PRED)-COND+1
#define QPAD  256      // per-m padded q rows (8*256 = 2048 total)
#define KPAD  448      // padded kpos (14 chunks of 32)

typedef _Float16 half8 __attribute__((ext_vector_type(8)));
typedef float f32x16 __attribute__((ext_vector_type(16)));

__device__ __forceinline__ f32x16 mfma_f16(half8 a, half8 b, f32x16 c) {
    return __builtin_amdgcn_mfma_f32_32x32x16_f16(a, b, c, 0, 0, 0);
}
__device__ __forceinline__ f32x16 zero16() {
    f32x16 z;
    #pragma unroll
    for (int i = 0; i < 16; i++) z[i] = 0.f;
    return z;
}

#define GLOAD_LDS16(g, l) __builtin_amdgcn_global_load_lds( \
    (const __attribute__((address_space(1))) void*)(g), \
    (__attribute__((address_space(3))) void*)(l), 16, 0, 0)

// ---------------- K0: cumsums, minmax offsets/scales, mc (mean conv) ----------------
__global__ void k0_scan(const float* __restrict__ q, const float* __restrict__ r,
                        float* cs_q, float* cs_r, float* mc,
                        float* q_off, float* q_scale, float* k_off, float* k_scale,
                        const float* __restrict__ mw, const float* __restrict__ mb) {
    __shared__ float x[512];
    __shared__ float s[512];
    __shared__ float P[256];
    int b = blockIdx.x, t = threadIdx.x;
    if (b < M_B) {
        // ---- query row b (len 256) ----
        x[t] = q[b * 256 + t];
        __syncthreads();
        s[t] = x[t];
        __syncthreads();
        for (int off = 1; off < 256; off <<= 1) {
            float v = (t >= off) ? s[t - off] : 0.f;
            __syncthreads();
            s[t] += v;
            __syncthreads();
        }
        cs_q[b * 256 + t] = s[t];
        // mc[t] = sum_j mw[j]*query[t+j-63] (zero pad) + m_bias
        float acc = mb[0];
        for (int j = 0; j < 64; j++) {
            int qi = t + j - 63;
            if (qi >= 0) acc += mw[j] * x[qi];
        }
        mc[b * 256 + t] = acc;
        // q offset/scale per qpos (all 256 padded rows)
        if (t < QN) {
            float mn = s[t], mx = s[t];
            for (int j = 1; j < 64; j++) {
                float v = s[t + j];
                mn = fminf(mn, v); mx = fmaxf(mx, v);
            }
            float sc = mx - mn; if (sc == 0.f) sc = 1.f;
            q_off[b * QPAD + t] = mn;
            q_scale[b * QPAD + t] = sc;
        } else {
            q_off[b * QPAD + t] = 0.f;
            q_scale[b * QPAD + t] = 1.f;
        }
    } else {
        // ---- ref row (len 512): pair-scan ----
        int n = b - M_B;
        x[t] = r[n * 512 + t];
        x[t + 256] = r[n * 512 + t + 256];
        __syncthreads();
        P[t] = x[2 * t] + x[2 * t + 1];
        __syncthreads();
        for (int off = 1; off < 256; off <<= 1) {
            float v = (t >= off) ? P[t - off] : 0.f;
            __syncthreads();
            P[t] += v;
            __syncthreads();
        }
        s[2 * t + 1] = P[t];
        s[2 * t]     = P[t] - x[2 * t + 1];
        __syncthreads();
        cs_r[n * 512 + t] = s[t];
        cs_r[n * 512 + t + 256] = s[t + 256];
        for (int p = t; p < KPAD; p += 256) {
            if (p < KN) {
                float mn = s[p], mx = s[p];
                for (int j = 1; j < 64; j++) {
                    float v = s[p + j];
                    mn = fminf(mn, v); mx = fmaxf(mx, v);
                }
                float sc = mx - mn; if (sc == 0.f) sc = 1.f;
                k_off[n * KPAD + p] = mn;
                k_scale[n * KPAD + p] = sc;
            } else {
                k_off[n * KPAD + p] = 0.f;
                k_scale[n * KPAD + p] = 1.f;
            }
        }
    }
}

// ---------------- K1: q features -> fp32 qfeat + frag-major f16 hi/lo q_hilo ----------------
// grid (8 m, 16 chunks of 16 qpos), 256 thr
__global__ void k1_qfeat(const float* __restrict__ cs_q, const float* __restrict__ q_off,
                         const float* __restrict__ q_scale,
                         const float* __restrict__ qw, const float* __restrict__ qb,
                         float* qfeat, _Float16* qg) {
    __shared__ float w[128 * 65];
    __shared__ float wsum[128];
    __shared__ float csS[80];
    __shared__ float offS[16], sclS[16];
    int m = blockIdx.x, chunk = blockIdx.y, t = threadIdx.x;
    int qbase = chunk * 16;
    for (int i = t; i < 8192; i += 256) {
        int h = i >> 6, j = i & 63;
        w[h * 65 + j] = qw[i];
    }
    if (t < 80) {
        int ci = qbase + t;
        csS[t] = (ci < 256) ? cs_q[m * 256 + ci] : 0.f;
    }
    if (t < 16) {
        int qpos = qbase + t;
        if (qpos < QN) { offS[t] = q_off[m * QPAD + qpos]; sclS[t] = q_scale[m * QPAD + qpos]; }
        else { offS[t] = 0.f; sclS[t] = 1.f; }
    }
    __syncthreads();
    if (t < 128) {
        float sm = 0.f;
        for (int j = 0; j < 64; j++) sm += w[t * 65 + j];
        wsum[t] = sm;
    }
    __syncthreads();
    int h = t & 127, ql0 = t >> 7;
    float bias = qb[h];
    int c = h >> 4, kh = (h >> 3) & 1, j5 = h & 7;
    for (int ql = ql0; ql < 16; ql += 2) {
        int qpos = qbase + ql;           // always < 256
        float val = 0.f;
        if (qpos < QN) {
            float raw = 0.f;
            #pragma unroll 8
            for (int j = 0; j < 64; j++) raw += w[h * 65 + j] * csS[ql + j];
            val = (raw - offS[ql] * wsum[h]) / sclS[ql] + bias;
        }
        qfeat[((size_t)m * QPAD + qpos) * 128 + h] = val;
        _Float16 hi = (_Float16)val;
        _Float16 lo = (_Float16)((val - (float)hi) * 1024.0f);
        int wv = (qpos >> 6) & 3, rr = (qpos >> 5) & 1, lr_ = qpos & 31;
        size_t fb = ((size_t)(m * 4 + wv) * 32) + (size_t)(rr * 8 + c) * 2;
        size_t li = (size_t)(kh * 32 + lr_) * 8 + j5;
        qg[fb * 512 + li] = hi;
        qg[(fb + 1) * 512 + li] = lo;
    }
}

// ---------------- K2: k/v features -> swizzled f16 hi/lo kg + fp32 vfeat ----------------
// grid (64 n, 7 chunks of 64 kpos), 256 thr
__global__ void k2_kv(const float* __restrict__ cs_r, const float* __restrict__ ref,
                      const float* __restrict__ k_off, const float* __restrict__ k_scale,
                      const float* __restrict__ kw, const float* __restrict__ kb,
                      const float* __restrict__ vw, const float* __restrict__ vb,
                      _Float16* kg, float* vfeat) {
    __shared__ float w[128 * 65];
    __shared__ float vwS[128 * 33];
    __shared__ float wsum[128];
    __shared__ float csS[128];
    __shared__ float refS[96];
    __shared__ float koS[64], ksS[64];
    int n = blockIdx.x, chunk = blockIdx.y, t = threadIdx.x;
    int kbase = chunk * 64;
    for (int i = t; i < 8192; i += 256) { int h = i >> 6, j = i & 63; w[h * 65 + j] = kw[i]; }
    for (int i = t; i < 4096; i += 256) { int h = i >> 5, j = i & 31; vwS[h * 33 + j] = vw[i]; }
    if (t < 128) { int ci = kbase + t; csS[t] = (ci < 512) ? cs_r[n * 512 + ci] : 0.f; }
    if (t < 96)  { int ri = 64 + kbase + t; refS[t] = (ri < 512) ? ref[n * 512 + ri] : 0.f; }
    if (t < 64) {
        int kp = kbase + t;
        if (kp < KN) { koS[t] = k_off[n * KPAD + kp]; ksS[t] = k_scale[n * KPAD + kp]; }
        else { koS[t] = 0.f; ksS[t] = 1.f; }
    }
    __syncthreads();
    if (t < 128) {
        float sm = 0.f;
        for (int j = 0; j < 64; j++) sm += w[t * 65 + j];
        wsum[t] = sm;
    }
    __syncthreads();
    int h = t & 127, kl0 = t >> 7;
    float kbia = kb[h], vbia = vb[h];
    int cb = h >> 3, j5 = h & 7;
    for (int kl = kl0; kl < 64; kl += 2) {
        int kp = kbase + kl;
        float kval = 0.f, vval = 0.f;
        if (kp < KN) {
            float kraw = 0.f;
            #pragma unroll 8
            for (int j = 0; j < 64; j++) kraw += w[h * 65 + j] * csS[kl + j];
            float vraw = 0.f;
            #pragma unroll 8
            for (int j = 0; j < 32; j++) vraw += vwS[h * 33 + j] * refS[kl + j];
            float inv = 1.f / ksS[kl];
            kval = (kraw - koS[kl] * wsum[h]) * inv + kbia;
            vval = vraw * inv + vbia;
        }
        _Float16 khi = (_Float16)kval;
        _Float16 klo = (_Float16)((kval - (float)khi) * 1024.0f);
        size_t rowb = ((size_t)n * KPAD + kp) * 256;
        int sw = kp & 31;
        kg[rowb + (size_t)((cb ^ sw) * 8) + j5] = khi;
        kg[rowb + (size_t)(((16 + cb) ^ sw) * 8) + j5] = klo;
        vfeat[((size_t)n * KPAD + kp) * 128 + h] = vval;
    }
}

// ---------------- K3: split-f16 MFMA score matmul + max/argmax over kpos ----------------
// grid 512 = 8 q-tiles * 64 n (n = blk&63 -> same-n blocks on same XCD), 256 thr = 4 waves.
// Each wave owns 64 q-rows in registers (32 half8 frags); K staged 32 kpos at a time
// into double-buffered LDS via global_load_lds; XOR-swizzled layout (baked by k2).
__launch_bounds__(256, 2)
__global__ void k3_score(const _Float16* __restrict__ qg, const _Float16* __restrict__ kg,
                         float* __restrict__ bscore, int* __restrict__ bidx) {
    __shared__ _Float16 Kbuf[2][32 * 256];   // 16 KB each
    const int blk = blockIdx.x;
    const int n = blk & 63, qt = blk >> 6;
    const int t = threadIdx.x, w = t >> 6, l = t & 63;
    const int lrow = l & 31, khalf = l >> 5;

    // Q fragments: [r=2][c=8][hi/lo=2], frag-major global layout -> fully coalesced
    half8 qf[2][8][2];
    {
        const half8* qb = (const half8*)qg + (size_t)(qt * 4 + w) * 32 * 64 + l;
        #pragma unroll
        for (int r = 0; r < 2; r++)
            #pragma unroll
            for (int c = 0; c < 8; c++)
                #pragma unroll
                for (int h = 0; h < 2; h++)
                    qf[r][c][h] = qb[((r * 8 + c) * 2 + h) * 64];
    }

    const _Float16* ksrc = kg + (size_t)n * KPAD * 256;

    float best[2][16];
    unsigned bkt[4] = {0u, 0u, 0u, 0u};
    #pragma unroll
    for (int r = 0; r < 2; r++)
        #pragma unroll
        for (int g = 0; g < 16; g++) best[r][g] = -INFINITY;

    // stage chunk 0 (16 KB, per-wave uniform base + lane*16)
    #pragma unroll
    for (int rd = 0; rd < 4; rd++) {
        int e = (rd * 4 + w) * 512 + l * 8;
        GLOAD_LDS16(ksrc + e, &Kbuf[0][0] + e);
    }

    for (int kt = 0; kt < 14; kt++) {
        __syncthreads();                       // drains vmcnt -> staged chunk kt ready
        if (kt < 13) {
            const _Float16* src = ksrc + (size_t)(kt + 1) * (32 * 256);
            _Float16* dst = &Kbuf[(kt + 1) & 1][0];
            #pragma unroll
            for (int rd = 0; rd < 4; rd++) {
                int e = (rd * 4 + w) * 512 + l * 8;
                GLOAD_LDS16(src + e, dst + e);
            }
        }
        const _Float16* kb = &Kbuf[kt & 1][0];
        f32x16 accH[2], accL[2];
        accH[0] = zero16(); accH[1] = zero16();
        accL[0] = zero16(); accL[1] = zero16();
        #pragma unroll
        for (int c = 0; c < 8; c++) {
            half8 bh = *(const half8*)(kb + lrow * 256 + (((c * 2 + khalf) ^ lrow) * 8));
            half8 bl = *(const half8*)(kb + lrow * 256 + (((16 + c * 2 + khalf) ^ lrow) * 8));
            #pragma unroll
            for (int r = 0; r < 2; r++) {
                accH[r] = mfma_f16(qf[r][c][0], bh, accH[r]);
                accL[r] = mfma_f16(qf[r][c][0], bl, accL[r]);
                accL[r] = mfma_f16(qf[r][c][1], bh, accL[r]);
            }
        }
        const int kp = kt * 32 + lrow;
        const bool valid = kp < KN;
        #pragma unroll
        for (int r = 0; r < 2; r++) {
            #pragma unroll
            for (int g = 0; g < 16; g++) {
                float s = accH[r][g] + accL[r][g] * (1.0f / 1024.0f);
                // strict > with ascending kp => numpy first-index tie-break per lane
                if (valid && (s > best[r][g])) {
                    best[r][g] = s;
                    const int slot = r * 16 + g;
                    const unsigned sh = (unsigned)(slot & 7) * 4u;
                    bkt[slot >> 3] = (bkt[slot >> 3] & ~(0xFu << sh)) | ((unsigned)kt << sh);
                }
            }
        }
    }

    // cross-lane argmax reduce (32 kpos-cols live in lanes of the same half)
    #pragma unroll
    for (int r = 0; r < 2; r++) {
        #pragma unroll
        for (int g = 0; g < 16; g++) {
            float s = best[r][g];
            const int slot = r * 16 + g;
            int ktb = (int)((bkt[slot >> 3] >> ((slot & 7) * 4)) & 0xFu);
            int kp = ktb * 32 + lrow;
            for (int msk = 1; msk < 32; msk <<= 1) {
                float os = __shfl_xor(s, msk, 64);
                int okp = __shfl_xor(kp, msk, 64);
                if (os > s || (os == s && okp < kp)) { s = os; kp = okp; }
            }
            if (lrow == 0) {
                int row = (g & 3) + 8 * (g >> 2) + 4 * khalf;
                int mq = qt * 256 + w * 64 + r * 32 + row;
                if ((mq & 255) < QN) {
                    bscore[(size_t)mq * 64 + n] = s;
                    bidx[(size_t)mq * 64 + n] = kp;
                }
            }
        }
    }
}

// ---------------- K4: softmax + gather-weight V + projection epilogue ----------------
__global__ void k4_out(const float* __restrict__ qfeat, const float* __restrict__ vfeat,
                       const float* __restrict__ bscore, const int* __restrict__ bidx,
                       const float* __restrict__ q_scale, const float* __restrict__ mc,
                       const float* __restrict__ mkey,
                       const float* __restrict__ ow, const float* __restrict__ ob,
                       float* out) {
    __shared__ float sL[64]; __shared__ int iL[64];
    __shared__ float rsL[64];
    __shared__ float redA[128];
    __shared__ float wL[128];
    int bid = blockIdx.x, t = threadIdx.x;
    int m = bid / QN, qpos = bid - m * QN;
    int mq = m * QPAD + qpos;
    if (t < 64) { sL[t] = bscore[(size_t)mq * 64 + t]; iL[t] = bidx[(size_t)mq * 64 + t]; }
    redA[t] = qfeat[(size_t)mq * 128 + t] * mkey[t];
    __syncthreads();
    for (int off = 64; off > 0; off >>= 1) {
        if (t < off) redA[t] += redA[t + off];
        __syncthreads();
    }
    float msv = redA[0];
    __syncthreads();
    redA[t] = (t < 64) ? sL[t] : -INFINITY;
    __syncthreads();
    for (int off = 64; off > 0; off >>= 1) {
        if (t < off) redA[t] = fmaxf(redA[t], redA[t + off]);
        __syncthreads();
    }
    float mx = fmaxf(redA[0], msv);
    __syncthreads();
    float e = (t < 64) ? expf(sL[t] - mx) : 0.f;
    redA[t] = e;
    if (t < 64) rsL[t] = e;
    __syncthreads();
    for (int off = 64; off > 0; off >>= 1) {
        if (t < off) redA[t] += redA[t + off];
        __syncthreads();
    }
    float ems = expf(msv - mx);
    float inv = 1.f / (redA[0] + ems);
    float msw = ems * inv;
    __syncthreads();
    if (t < 64) rsL[t] *= inv;
    __syncthreads();
    float acc = 0.f;
    for (int nn = 0; nn < 64; nn++) {
        acc += rsL[nn] * vfeat[((size_t)nn * KPAD + iL[nn]) * 128 + t];
    }
    wL[t] = acc;
    __syncthreads();
    if (t < 32) {
        float p = 0.f;
        #pragma unroll 8
        for (int h = 0; h < 128; h++) p += wL[h] * ow[t * 128 + h];
        p += (1.f - msw) * ob[t];
        float outv = q_scale[mq] * p + msw * mc[m * 256 + 32 + qpos + t];
        out[((size_t)m * QN + qpos) * 32 + t] = outv;
    }
}

extern "C" void kernel_launch(void* const* d_in, const int* in_sizes, int n_in,
                              void* d_out, int out_size, void* d_ws, size_t ws_size,
                              hipStream_t stream) {
    const float* query = (const float*)d_in[0];
    const float* ref   = (const float*)d_in[1];
    const float* qw    = (const float*)d_in[2];
    const float* qb    = (const float*)d_in[3];
    const float* kw    = (const float*)d_in[4];
    const float* kb    = (const float*)d_in[5];
    const float* vw    = (const float*)d_in[6];
    const float* vb    = (const float*)d_in[7];
    const float* mw    = (const float*)d_in[8];
    const float* mb    = (const float*)d_in[9];
    const float* ow    = (const float*)d_in[10];
    const float* ob    = (const float*)d_in[11];
    const float* mkey  = (const float*)d_in[12];
    float* out = (float*)d_out;

    // workspace layout (floats); total ~8.23M floats = 32.9 MB
    float* ws = (float*)d_ws;
    float* cs_q    = ws;                        // 2048
    float* cs_r    = cs_q + 2048;               // 32768
    float* mc      = cs_r + 32768;              // 2048
    float* q_off   = mc + 2048;                 // 8*256 = 2048
    float* q_scale = q_off + 2048;              // 2048
    float* k_off   = q_scale + 2048;            // 64*448 = 28672
    float* k_scale = k_off + 28672;             // 28672
    float* qfeat   = k_scale + 28672;           // 2048*128 = 262144
    float* bscore  = qfeat + 262144;            // 2048*64 = 131072
    int*   bidx    = (int*)(bscore + 131072);   // 131072
    _Float16* qg   = (_Float16*)(bscore + 262144);        // 2048*128*2 f16 = 262144 fl
    _Float16* kg   = (_Float16*)(bscore + 262144 + 262144); // 64*448*256 f16 = 3670016 fl
    float* vfeat   = bscore + 262144 + 262144 + 3670016;  // 64*448*128 = 3670016 fl

    hipLaunchKernelGGL(k0_scan, dim3(72), dim3(256), 0, stream,
                       query, ref, cs_q, cs_r, mc, q_off, q_scale, k_off, k_scale, mw, mb);
    hipLaunchKernelGGL(k1_qfeat, dim3(8, 16), dim3(256), 0, stream,
                       cs_q, q_off, q_scale, qw, qb, qfeat, qg);
    hipLaunchKernelGGL(k2_kv, dim3(64, 7), dim3(256), 0, stream,
                       cs_r, ref, k_off, k_scale, kw, kb, vw, vb, kg, vfeat);
    hipLaunchKernelGGL(k3_score, dim3(512), dim3(256), 0, stream,
                       qg, kg, bscore, bidx);
    hipLaunchKernelGGL(k4_out, dim3(QN * M_B), dim3(128), 0, stream,
                       qfeat, vfeat, bscore, bidx, q_scale, mc, mkey, ow, ob, out);
}